// Round 2
// baseline (80.433 us; speedup 1.0000x reference)
//
#include <hip/hip_runtime.h>
#include <math.h>

// LML layer: per row solve sum_j sigmoid(x_j + nu) = N (N=5), output sigmoid(x+nu).
// One wave (64 lanes) per row; 16 elements/lane in registers as E_j = exp(+x_j).
//
// u = exp(-nu):  sigmoid(x_j+nu) = E_j/(E_j+u).
//   g(u) = sum E/(E+u) - N is convex, strictly decreasing for u>0 (any data).
//   u0 = (sum E)/N  =>  g(u0) < 0; convexity => plain Newton globally
//   convergent (one left overshoot, then monotone from the left).
//
// R1 changes vs previous (theory: latency-bound serial chain + occupancy):
//  * Wave reductions are now DS-free: 4 DPP adds (quad_perm/row_mirror family,
//    VALU rate) + permlane16_swap + permlane32_swap (gfx950 VALU cross-row).
//    Was: 6 x __shfl_xor (ds_bpermute, ~100cy latency each) x 3 reductions.
//  * Dropped t[16]/tr[16] Taylor epilogue (-32 VGPRs): compute u2 = u1 + delta
//    and recompute y = E*rcp(E+u2) directly (16 rcp on idle trans pipe).
//    This is exactly what the Taylor step approximated -> accuracy same/better.
//  Expect ~40-60 VGPRs -> 8 waves/SIMD, and a ~1500cy serial chain vs ~2700.
//
// All reduction adds are commutative pairwise sums -> bitwise identical across
// lanes -> control flow stays wave-uniform. No LDS, no barriers. NT stores.

constexpr int COLS = 1024;
constexpr int NTOP = 5;
constexpr int VPL  = COLS / 64;   // 16 values per lane
constexpr int WPB  = 4;           // waves (rows) per block

typedef float vfloat4 __attribute__((ext_vector_type(4)));
typedef unsigned uivec2 __attribute__((ext_vector_type(2)));

__device__ __forceinline__ float f_as(unsigned i) { return __builtin_bit_cast(float, i); }
__device__ __forceinline__ unsigned u_as(float f) { return __builtin_bit_cast(unsigned, f); }

// v += v[lane ^ k] via DPP (VALU rate, no DS):
//   0xB1 = quad_perm(1,0,3,2)  -> xor1
//   0x4E = quad_perm(2,3,0,1)  -> xor2
//   0x141 = row_half_mirror    -> xor7 within 8 (completes 8-group after xor1,2)
//   0x140 = row_mirror         -> xor15 within 16 (completes 16-row)
template <int CTRL>
__device__ __forceinline__ float dpp_add(float v) {
    int t = __builtin_amdgcn_update_dpp(0, (int)u_as(v), CTRL, 0xF, 0xF, true);
    return v + f_as((unsigned)t);
}

// cross-16-row add: v + v[lane^16], all lanes, VALU-only on gfx950
__device__ __forceinline__ float cross16_add(float v) {
#if __has_builtin(__builtin_amdgcn_permlane16_swap)
    uivec2 r = __builtin_amdgcn_permlane16_swap(u_as(v), u_as(v), false, false);
    return f_as(r.x) + f_as(r.y);
#else
    return v + __shfl_xor(v, 16, 64);
#endif
}
// cross-32 add: v + v[lane^32]
__device__ __forceinline__ float cross32_add(float v) {
#if __has_builtin(__builtin_amdgcn_permlane32_swap)
    uivec2 r = __builtin_amdgcn_permlane32_swap(u_as(v), u_as(v), false, false);
    return f_as(r.x) + f_as(r.y);
#else
    return v + __shfl_xor(v, 32, 64);
#endif
}

__device__ __forceinline__ float wave_sum_fast(float v) {
    v = dpp_add<0xB1>(v);
    v = dpp_add<0x4E>(v);
    v = dpp_add<0x141>(v);
    v = dpp_add<0x140>(v);
    v = cross16_add(v);
    v = cross32_add(v);
    return v;
}

// Two interleaved reductions for ILP on the short DPP chain.
__device__ __forceinline__ void wave_sum2_fast(float& a, float& b) {
    a = dpp_add<0xB1>(a);  b = dpp_add<0xB1>(b);
    a = dpp_add<0x4E>(a);  b = dpp_add<0x4E>(b);
    a = dpp_add<0x141>(a); b = dpp_add<0x141>(b);
    a = dpp_add<0x140>(a); b = dpp_add<0x140>(b);
    a = cross16_add(a);    b = cross16_add(b);
    a = cross32_add(a);    b = cross32_add(b);
}

__global__ __launch_bounds__(WPB * 64) void lml_kernel(
        const float* __restrict__ x, float* __restrict__ y, int rows) {
    const int wave = threadIdx.x >> 6;
    const int lane = threadIdx.x & 63;
    const int row  = blockIdx.x * WPB + wave;
    if (row >= rows) return;

    const float* xr = x + (size_t)row * COLS;
    float*       yr = y + (size_t)row * COLS;

    constexpr float L2E = 1.4426950408889634f;   // log2(e)

    // ---- pass 1: issue all 4 loads, then exp + row-sum of E ----
    vfloat4 v0 = *reinterpret_cast<const vfloat4*>(xr + 0 * 256 + lane * 4);
    vfloat4 v1 = *reinterpret_cast<const vfloat4*>(xr + 1 * 256 + lane * 4);
    vfloat4 v2 = *reinterpret_cast<const vfloat4*>(xr + 2 * 256 + lane * 4);
    vfloat4 v3 = *reinterpret_cast<const vfloat4*>(xr + 3 * 256 + lane * 4);

    float E[VPL];
    float s0 = 0.0f;
    {
        const vfloat4 vv[4] = {v0, v1, v2, v3};
#pragma unroll
        for (int w = 0; w < 4; ++w) {
            float e0 = __builtin_amdgcn_exp2f(vv[w].x * L2E);
            float e1 = __builtin_amdgcn_exp2f(vv[w].y * L2E);
            float e2 = __builtin_amdgcn_exp2f(vv[w].z * L2E);
            float e3 = __builtin_amdgcn_exp2f(vv[w].w * L2E);
            E[w * 4 + 0] = e0; E[w * 4 + 1] = e1;
            E[w * 4 + 2] = e2; E[w * 4 + 3] = e3;
            s0 += (e0 + e1) + (e2 + e3);
        }
    }
    s0 = wave_sum_fast(s0);                // identical on all lanes

    float u = s0 * (1.0f / (float)NTOP);   // u0: g(u0) < 0 guaranteed

    // ---- Newton iteration A ----
    {
        float G = 0.0f, H = 0.0f;
#pragma unroll
        for (int j = 0; j < VPL; ++j) {
            float r = __builtin_amdgcn_rcpf(E[j] + u);
            float t = E[j] * r;            // sigmoid value
            G += t;
            H = fmaf(t, r, H);             // -g'(u) = sum E/(E+u)^2
        }
        wave_sum2_fast(G, H);
        u = fmaf(G - (float)NTOP, __builtin_amdgcn_rcpf(H), u);
        u = fmaxf(u, 1e-30f);              // paranoia, never hit for sane data
    }

    // ---- Newton iteration B ----
    {
        float G = 0.0f, H = 0.0f;
#pragma unroll
        for (int j = 0; j < VPL; ++j) {
            float r = __builtin_amdgcn_rcpf(E[j] + u);
            float t = E[j] * r;
            G += t;
            H = fmaf(t, r, H);
        }
        wave_sum2_fast(G, H);
        u = fmaf(G - (float)NTOP, __builtin_amdgcn_rcpf(H), u);
        u = fmaxf(u, 1e-30f);
    }

    // ---- epilogue: y = E/(E+u2), streamed out ----
#pragma unroll
    for (int w = 0; w < VPL / 4; ++w) {
        vfloat4 o;
        o.x = E[w * 4 + 0] * __builtin_amdgcn_rcpf(E[w * 4 + 0] + u);
        o.y = E[w * 4 + 1] * __builtin_amdgcn_rcpf(E[w * 4 + 1] + u);
        o.z = E[w * 4 + 2] * __builtin_amdgcn_rcpf(E[w * 4 + 2] + u);
        o.w = E[w * 4 + 3] * __builtin_amdgcn_rcpf(E[w * 4 + 3] + u);
        __builtin_nontemporal_store(o, reinterpret_cast<vfloat4*>(yr + w * 256 + lane * 4));
    }
}

extern "C" void kernel_launch(void* const* d_in, const int* in_sizes, int n_in,
                              void* d_out, int out_size, void* d_ws, size_t ws_size,
                              hipStream_t stream) {
    const float* x = (const float*)d_in[0];
    float* y = (float*)d_out;
    const int rows = in_sizes[0] / COLS;   // 8192
    const int grid = (rows + WPB - 1) / WPB;
    lml_kernel<<<grid, WPB * 64, 0, stream>>>(x, y, rows);
}